// Round 3
// baseline (741.648 us; speedup 1.0000x reference)
//
#include <hip/hip_runtime.h>
#include <hip/hip_bf16.h>

typedef __bf16 bf16x8 __attribute__((ext_vector_type(8)));
typedef __bf16 bf16x4 __attribute__((ext_vector_type(4)));
typedef float  floatx4 __attribute__((ext_vector_type(4)));

// Problem constants: B=2, C=128, N = 16*16*16 = 4096
// ws layout: [flag int, 256B pad] | qT[b][n][c] bf16 | kT[b][m][c] bf16 | vT2[b][c][m] bf16
// (256 B + 3 * 2 MB = 6.3 MB)

// ---------------- Kernel 0: input dtype probe ----------------
// Reads 64 words of Wq. If data is bf16, low 16 bits of each word are a sane
// bf16 (~N(0,0.09) -> exponent near 120). If data is fp32, low 16 bits are
// mantissa garbage -> exponent uniform -> ~16% in range. flag=1 means bf16.
__global__ void probe_kernel(const unsigned* __restrict__ Wq_bits,
                             int* __restrict__ flag)
{
    if (threadIdx.x == 0) {
        int sane = 0;
        for (int i = 0; i < 64; ++i) {
            const unsigned ex = (Wq_bits[i] >> 7) & 0xFFu;  // bf16 exp of low half
            if (ex >= 100u && ex <= 140u) ++sane;
        }
        *flag = (sane >= 48) ? 1 : 0;
    }
}

// ---------------- Kernel 1: QKV projection (dual-dtype) ----------------
// grid (N/8, 3, B), block 256. Thread: o = tid&127, nl = tid>>7 -> 4 n each.
__global__ __launch_bounds__(256) void proj_kernel(
    const void* __restrict__ x,
    const void* __restrict__ Wq, const void* __restrict__ bq,
    const void* __restrict__ Wk, const void* __restrict__ bk,
    const void* __restrict__ Wv, const void* __restrict__ bv,
    const int* __restrict__ flag,
    __bf16* __restrict__ qT, __bf16* __restrict__ kT, __bf16* __restrict__ vT2)
{
    constexpr int C = 128, N = 4096;
    const int isbf = *flag;
    const int b = blockIdx.z;
    const int which = blockIdx.y;          // 0=q 1=k 2=v
    const int n_base = blockIdx.x * 8;
    const int tid = threadIdx.x;
    const void* W    = (which == 0) ? Wq : (which == 1) ? Wk : Wv;
    const void* bias = (which == 0) ? bq : (which == 1) ? bk : bv;

    __shared__ float x_s[128][8];          // x column tile, fp32
    if (tid < 128) {
        const size_t off = (size_t)(b * C + tid) * N + n_base;
        if (isbf) {
            bf16x8 xv = *(const bf16x8*)((const __bf16*)x + off);
            #pragma unroll
            for (int j = 0; j < 8; ++j) x_s[tid][j] = (float)xv[j];
        } else {
            const float* xf = (const float*)x + off;
            #pragma unroll
            for (int j = 0; j < 8; ++j) x_s[tid][j] = xf[j];
        }
    }
    __syncthreads();

    const int o  = tid & 127;
    const int nl = tid >> 7;               // 0..1
    float acc[4] = {0.f, 0.f, 0.f, 0.f};
    for (int c8 = 0; c8 < 16; ++c8) {
        float wv[8];
        if (isbf) {
            bf16x8 w = *(const bf16x8*)((const __bf16*)W + (size_t)o * C + (c8 << 3));
            #pragma unroll
            for (int j = 0; j < 8; ++j) wv[j] = (float)w[j];
        } else {
            const float* wf = (const float*)W + (size_t)o * C + (c8 << 3);
            #pragma unroll
            for (int j = 0; j < 8; ++j) wv[j] = wf[j];
        }
        #pragma unroll
        for (int j = 0; j < 8; ++j) {
            const floatx4 xv = *(const floatx4*)(&x_s[c8 * 8 + j][nl * 4]);
            #pragma unroll
            for (int i = 0; i < 4; ++i) acc[i] += wv[j] * xv[i];
        }
    }
    const float bb = isbf ? (float)((const __bf16*)bias)[o] : ((const float*)bias)[o];
    if (which < 2) {
        __bf16* dst = (which == 0) ? qT : kT;
        #pragma unroll
        for (int j = 0; j < 4; ++j) {
            const int n = n_base + nl * 4 + j;
            dst[(size_t)(b * N + n) * C + o] = (__bf16)(acc[j] + bb);
        }
    } else {
        bf16x4 tmp;
        #pragma unroll
        for (int j = 0; j < 4; ++j) tmp[j] = (__bf16)(acc[j] + bb);
        *(bf16x4*)(vT2 + (size_t)(b * C + o) * N + n_base + nl * 4) = tmp;
    }
}

// ---------------- Kernel 2: flash attention, final output ----------------
// grid (N/32, B), block 128 (2 waves, each owns 16 n-columns).
// Transposed MFMA roles: A = K/V tile (rows = m or c), B = Q/P (cols = n).
// D C-layout: row = quad*4+reg (m- or c-local), col = lane&15 (n-local).
__global__ __launch_bounds__(128, 2) void flash_final(
    const __bf16* __restrict__ qT, const __bf16* __restrict__ kT,
    const __bf16* __restrict__ vT2, const void* __restrict__ x,
    const void* __restrict__ gamma_p, const int* __restrict__ flag,
    void* __restrict__ out)
{
    constexpr int C = 128, N = 4096;
    const int isbf = *flag;
    const int b = blockIdx.y;
    const int n0 = blockIdx.x * 32;
    const int tid = threadIdx.x;
    const int wave = tid >> 6;             // 0..1
    const int lane = tid & 63;
    const int l15 = lane & 15;
    const int quad = lane >> 4;

    __shared__ __bf16 q_s[32][136];        // q_s[n-local][c]
    __shared__ __bf16 k_s[64][136];        // k_s[m-local][c]
    __shared__ __bf16 v_s[128][72];        // v_s[c][m-local]
    __shared__ __bf16 p_s[2][16][72];      // per-wave P^T: [n-local][m-local]

    for (int i = tid; i < 32 * 16; i += 128) {
        const int r = i >> 4, cc8 = (i & 15) << 3;
        *(bf16x8*)(&q_s[r][cc8]) =
            *(const bf16x8*)(qT + ((size_t)(b * N + n0 + r) * C + cc8));
    }

    float m_i = -1e30f, l_i = 0.f;
    floatx4 Oacc[8];                       // O^T[c = ct*16+quad*4+r][n = l15]
    const floatx4 fz = {0.f, 0.f, 0.f, 0.f};
    #pragma unroll
    for (int t = 0; t < 8; ++t) Oacc[t] = fz;

    for (int it = 0; it < N / 64; ++it) {
        const int m0 = it * 64;
        __syncthreads();
        for (int i = tid; i < 64 * 16; i += 128) {
            const int r = i >> 4, cc8 = (i & 15) << 3;
            *(bf16x8*)(&k_s[r][cc8]) =
                *(const bf16x8*)(kT + ((size_t)(b * N + m0 + r) * C + cc8));
        }
        for (int i = tid; i < 128 * 8; i += 128) {
            const int c = i >> 3, mm = (i & 7) << 3;
            *(bf16x8*)(&v_s[c][mm]) =
                *(const bf16x8*)(vT2 + ((size_t)(b * C + c) * N + m0 + mm));
        }
        __syncthreads();

        // S^T = K Q^T : S[ct][r] -> m = ct*16+quad*4+r, n = wave*16+l15
        floatx4 S[4];
        #pragma unroll
        for (int ct = 0; ct < 4; ++ct) S[ct] = fz;
        #pragma unroll
        for (int kk = 0; kk < 4; ++kk) {
            bf16x8 qb = *(bf16x8*)(&q_s[wave * 16 + l15][kk * 32 + quad * 8]);
            #pragma unroll
            for (int ct = 0; ct < 4; ++ct) {
                bf16x8 a = *(bf16x8*)(&k_s[ct * 16 + l15][kk * 32 + quad * 8]);
                S[ct] = __builtin_amdgcn_mfma_f32_16x16x32_bf16(a, qb, S[ct], 0, 0, 0);
            }
        }

        float rmax = -1e30f;
        #pragma unroll
        for (int ct = 0; ct < 4; ++ct)
            #pragma unroll
            for (int r = 0; r < 4; ++r) {
                const float v = S[ct][r] * 1.3f;
                S[ct][r] = v;
                rmax = fmaxf(rmax, v);
            }
        rmax = fmaxf(rmax, __shfl_xor(rmax, 16, 64));
        rmax = fmaxf(rmax, __shfl_xor(rmax, 32, 64));

        const float mn = fmaxf(m_i, rmax);
        const float alpha = __expf(m_i - mn);
        m_i = mn;

        float rsum = 0.f;
        #pragma unroll
        for (int ct = 0; ct < 4; ++ct)
            #pragma unroll
            for (int r = 0; r < 4; ++r) {
                const float p = __expf(S[ct][r] - m_i);
                S[ct][r] = p;
                rsum += p;
            }
        rsum += __shfl_xor(rsum, 16, 64);
        rsum += __shfl_xor(rsum, 32, 64);
        l_i = l_i * alpha + rsum;

        #pragma unroll
        for (int t = 0; t < 8; ++t)
            #pragma unroll
            for (int r = 0; r < 4; ++r) Oacc[t][r] *= alpha;

        #pragma unroll
        for (int ct = 0; ct < 4; ++ct)
            #pragma unroll
            for (int r = 0; r < 4; ++r)
                p_s[wave][l15][ct * 16 + quad * 4 + r] = (__bf16)S[ct][r];

        // O^T += V P^T : A = V[c][m], B = P^T[n][m]
        #pragma unroll
        for (int kk = 0; kk < 2; ++kk) {
            bf16x8 pb = *(bf16x8*)(&p_s[wave][l15][kk * 32 + quad * 8]);
            #pragma unroll
            for (int ct = 0; ct < 8; ++ct) {
                bf16x8 a = *(bf16x8*)(&v_s[ct * 16 + l15][kk * 32 + quad * 8]);
                Oacc[ct] = __builtin_amdgcn_mfma_f32_16x16x32_bf16(a, pb, Oacc[ct], 0, 0, 0);
            }
        }
    }

    // epilogue: out[b][c][n] = x + gamma * O / l   (dtype per flag)
    const float inv = 1.f / l_i;
    const float gamma = isbf ? (float)((const __bf16*)gamma_p)[0]
                             : ((const float*)gamma_p)[0];
    const int n = n0 + wave * 16 + l15;
    #pragma unroll
    for (int ct = 0; ct < 8; ++ct)
        #pragma unroll
        for (int r = 0; r < 4; ++r) {
            const int c = ct * 16 + quad * 4 + r;
            const size_t idx = ((size_t)b * C + c) * N + n;
            const float xv = isbf ? (float)((const __bf16*)x)[idx]
                                  : ((const float*)x)[idx];
            const float res = xv + gamma * Oacc[ct][r] * inv;
            if (isbf) ((__bf16*)out)[idx] = (__bf16)res;
            else      ((float*)out)[idx]  = res;
        }
}

extern "C" void kernel_launch(void* const* d_in, const int* in_sizes, int n_in,
                              void* d_out, int out_size, void* d_ws, size_t ws_size,
                              hipStream_t stream) {
    const void* x     = d_in[0];
    const void* Wq    = d_in[1];
    const void* bq    = d_in[2];
    const void* Wk    = d_in[3];
    const void* bk    = d_in[4];
    const void* Wv    = d_in[5];
    const void* bv    = d_in[6];
    const void* gamma = d_in[7];

    constexpr int Bn = 2, C = 128, N = 4096;
    int*    flag = (int*)d_ws;
    __bf16* qT   = (__bf16*)((char*)d_ws + 256);
    __bf16* kT   = qT + (size_t)Bn * N * C;
    __bf16* vT2  = kT + (size_t)Bn * N * C;

    probe_kernel<<<1, 64, 0, stream>>>((const unsigned*)Wq, flag);
    proj_kernel<<<dim3(N / 8, 3, Bn), 256, 0, stream>>>(
        x, Wq, bq, Wk, bk, Wv, bv, flag, qT, kT, vT2);
    flash_final<<<dim3(N / 32, Bn), 128, 0, stream>>>(
        qT, kT, vT2, x, gamma, flag, d_out);
}

// Round 4
// 202.797 us; speedup vs baseline: 3.6571x; 3.6571x over previous
//
#include <hip/hip_runtime.h>
#include <hip/hip_bf16.h>

typedef __bf16 bf16x8 __attribute__((ext_vector_type(8)));
typedef __bf16 bf16x4 __attribute__((ext_vector_type(4)));
typedef float  floatx4 __attribute__((ext_vector_type(4)));

// Problem constants: B=2, C=128, N = 16*16*16 = 4096. Inputs fp32, output fp32.
// ws (6.3 MB): qT[b][n][c] bf16 | kT[b][m][c] bf16 | vT2[b][c][m] bf16

// ---------------- Kernel 1: QKV projection (fp32 in, bf16 out) ----------------
// grid (N/32, 3, B), block 256. Thread: o = tid&127 (out channel), half = tid>>7.
__global__ __launch_bounds__(256) void proj_kernel(
    const float* __restrict__ x,
    const float* __restrict__ Wq, const float* __restrict__ bq,
    const float* __restrict__ Wk, const float* __restrict__ bk,
    const float* __restrict__ Wv, const float* __restrict__ bv,
    __bf16* __restrict__ qT, __bf16* __restrict__ kT, __bf16* __restrict__ vT2)
{
    constexpr int C = 128, N = 4096;
    const int b = blockIdx.z;
    const int which = blockIdx.y;          // 0=q 1=k 2=v
    const int n_base = blockIdx.x * 32;
    const int tid = threadIdx.x;
    const float* W    = (which == 0) ? Wq : (which == 1) ? Wk : Wv;
    const float* bias = (which == 0) ? bq : (which == 1) ? bk : bv;

    __shared__ float x_s[128][36];         // pad 36 -> 16B-aligned rows
    {
        const int row = tid & 127, hf = tid >> 7;
        const float* src = x + (size_t)(b * C + row) * N + n_base + hf * 16;
        #pragma unroll
        for (int j = 0; j < 4; ++j)
            *(float4*)(&x_s[row][hf * 16 + j * 4]) = *(const float4*)(src + j * 4);
    }
    __syncthreads();

    const int o  = tid & 127;
    const int hf = tid >> 7;               // n-half: 16 n each
    float acc[16];
    #pragma unroll
    for (int i = 0; i < 16; ++i) acc[i] = 0.f;

    for (int c4 = 0; c4 < 32; ++c4) {
        const float4 w4 = *(const float4*)(W + (size_t)o * C + c4 * 4);
        #pragma unroll
        for (int j = 0; j < 4; ++j) {
            const float wj = (&w4.x)[j];
            #pragma unroll
            for (int i4 = 0; i4 < 4; ++i4) {
                const float4 xv = *(const float4*)(&x_s[c4 * 4 + j][hf * 16 + i4 * 4]);
                acc[i4 * 4 + 0] += wj * xv.x;
                acc[i4 * 4 + 1] += wj * xv.y;
                acc[i4 * 4 + 2] += wj * xv.z;
                acc[i4 * 4 + 3] += wj * xv.w;
            }
        }
    }
    const float bb = bias[o];
    if (which < 2) {                       // q,k: n-major [b][n][c]
        __bf16* dst = (which == 0) ? qT : kT;
        #pragma unroll
        for (int i = 0; i < 16; ++i) {
            const int n = n_base + hf * 16 + i;
            dst[(size_t)(b * N + n) * C + o] = (__bf16)(acc[i] + bb);
        }
    } else {                               // v: c-major [b][c][m]
        bf16x8 t0, t1;
        #pragma unroll
        for (int i = 0; i < 8; ++i) { t0[i] = (__bf16)(acc[i] + bb); t1[i] = (__bf16)(acc[8 + i] + bb); }
        __bf16* dst = vT2 + (size_t)(b * C + o) * N + n_base + hf * 16;
        *(bf16x8*)(dst)     = t0;
        *(bf16x8*)(dst + 8) = t1;
    }
}

// ---------------- Kernel 2: flash attention, barrier-free m-loop ----------------
// grid (N/16, B), block 512 = 8 waves. All 8 waves share the SAME 16 n-columns
// (cols = l15); wave w owns m-split [w*512, (w+1)*512). K/V fragments load
// straight from global (16B contiguous per lane) -> NO __syncthreads in m-loop.
// Transposed MFMA roles: D rows = m (QK) or c (PV), cols = n. Softmax state is
// one scalar per lane. Cross-wave merge via LDS at the end.
__global__ __launch_bounds__(512, 4) void flash_kernel(
    const __bf16* __restrict__ qT, const __bf16* __restrict__ kT,
    const __bf16* __restrict__ vT2, const float* __restrict__ x,
    const float* __restrict__ gamma_p, float* __restrict__ out)
{
    constexpr int C = 128, N = 4096;
    const int b = blockIdx.y;
    const int n0 = blockIdx.x * 16;
    const int tid = threadIdx.x;
    const int wave = tid >> 6;             // 0..7 = m-split
    const int lane = tid & 63;
    const int l15 = lane & 15;             // n within tile
    const int quad = lane >> 4;

    __shared__ __bf16 q_s[16][136];
    __shared__ __bf16 p_s[8][16][72];      // per-wave P^T [n][m-local]
    __shared__ float  sm_m[8][16], sm_l[8][16];
    __shared__ __bf16 comb[8][16][132];    // per-wave scaled O^T [n][c]

    if (tid < 256) {
        const int r = tid >> 4, c8 = (tid & 15) << 3;
        *(bf16x8*)(&q_s[r][c8]) =
            *(const bf16x8*)(qT + ((size_t)(b * N + n0 + r) * C + c8));
    }
    __syncthreads();

    bf16x8 qb[4];
    #pragma unroll
    for (int kk = 0; kk < 4; ++kk)
        qb[kk] = *(bf16x8*)(&q_s[l15][kk * 32 + quad * 8]);

    float m_i = -1e30f, l_i = 0.f;
    floatx4 Oacc[8];
    const floatx4 fz = {0.f, 0.f, 0.f, 0.f};
    #pragma unroll
    for (int t = 0; t < 8; ++t) Oacc[t] = fz;

    const __bf16* kB = kT  + (size_t)b * N * C;
    const __bf16* vB = vT2 + (size_t)b * C * N;

    for (int it = 0; it < 8; ++it) {
        const int m0 = wave * 512 + it * 64;

        // S^T = K Q^T : S[ct] rows m = m0+ct*16+quad*4+r, col n = n0+l15
        floatx4 S[4];
        #pragma unroll
        for (int ct = 0; ct < 4; ++ct) S[ct] = fz;
        #pragma unroll
        for (int kk = 0; kk < 4; ++kk)
            #pragma unroll
            for (int ct = 0; ct < 4; ++ct) {
                const bf16x8 a = *(const bf16x8*)(kB + (size_t)(m0 + ct * 16 + l15) * C + kk * 32 + quad * 8);
                S[ct] = __builtin_amdgcn_mfma_f32_16x16x32_bf16(a, qb[kk], S[ct], 0, 0, 0);
            }

        float rmax = -1e30f;
        #pragma unroll
        for (int ct = 0; ct < 4; ++ct)
            #pragma unroll
            for (int r = 0; r < 4; ++r) {
                const float v = S[ct][r] * 1.3f;
                S[ct][r] = v;
                rmax = fmaxf(rmax, v);
            }
        rmax = fmaxf(rmax, __shfl_xor(rmax, 16, 64));
        rmax = fmaxf(rmax, __shfl_xor(rmax, 32, 64));

        const float mn = fmaxf(m_i, rmax);
        const float alpha = __expf(m_i - mn);
        m_i = mn;

        float rsum = 0.f;
        #pragma unroll
        for (int ct = 0; ct < 4; ++ct)
            #pragma unroll
            for (int r = 0; r < 4; ++r) {
                const float p = __expf(S[ct][r] - m_i);
                S[ct][r] = p;
                rsum += p;
            }
        rsum += __shfl_xor(rsum, 16, 64);
        rsum += __shfl_xor(rsum, 32, 64);
        l_i = l_i * alpha + rsum;

        #pragma unroll
        for (int t = 0; t < 8; ++t)
            #pragma unroll
            for (int r = 0; r < 4; ++r) Oacc[t][r] *= alpha;

        // P^T -> wave-private LDS (packed 8B writes), no barrier needed
        #pragma unroll
        for (int ct = 0; ct < 4; ++ct) {
            bf16x4 pk;
            #pragma unroll
            for (int r = 0; r < 4; ++r) pk[r] = (__bf16)S[ct][r];
            *(bf16x4*)(&p_s[wave][l15][ct * 16 + quad * 4]) = pk;
        }

        // O^T += V P^T
        #pragma unroll
        for (int kk = 0; kk < 2; ++kk) {
            const bf16x8 pb = *(bf16x8*)(&p_s[wave][l15][kk * 32 + quad * 8]);
            #pragma unroll
            for (int ct = 0; ct < 8; ++ct) {
                const bf16x8 a = *(const bf16x8*)(vB + (size_t)(ct * 16 + l15) * N + m0 + kk * 32 + quad * 8);
                Oacc[ct] = __builtin_amdgcn_mfma_f32_16x16x32_bf16(a, pb, Oacc[ct], 0, 0, 0);
            }
        }
    }

    // ---- cross-wave online-softmax merge ----
    if (quad == 0) { sm_m[wave][l15] = m_i; sm_l[wave][l15] = l_i; }
    __syncthreads();

    float M = -1e30f;
    #pragma unroll
    for (int w = 0; w < 8; ++w) M = fmaxf(M, sm_m[w][l15]);
    float L = 0.f;
    #pragma unroll
    for (int w = 0; w < 8; ++w) L += __expf(sm_m[w][l15] - M) * sm_l[w][l15];
    const float sc = __expf(m_i - M) / L;

    #pragma unroll
    for (int ct = 0; ct < 8; ++ct) {
        bf16x4 ov;
        #pragma unroll
        for (int r = 0; r < 4; ++r) ov[r] = (__bf16)(Oacc[ct][r] * sc);
        *(bf16x4*)(&comb[wave][l15][ct * 16 + quad * 4]) = ov;
    }
    __syncthreads();

    // reduce 8 waves + epilogue: thread -> (n = tid&15, c-group = tid>>4)
    const int nl = tid & 15, cg = tid >> 4;    // cg 0..31 -> 4 c each
    const float gamma = gamma_p[0];
    float Of[4] = {0.f, 0.f, 0.f, 0.f};
    #pragma unroll
    for (int w = 0; w < 8; ++w) {
        const bf16x4 cv = *(bf16x4*)(&comb[w][nl][cg * 4]);
        #pragma unroll
        for (int j = 0; j < 4; ++j) Of[j] += (float)cv[j];
    }
    #pragma unroll
    for (int j = 0; j < 4; ++j) {
        const int c = cg * 4 + j;
        const size_t idx = ((size_t)b * C + c) * N + n0 + nl;
        out[idx] = x[idx] + gamma * Of[j];
    }
}

extern "C" void kernel_launch(void* const* d_in, const int* in_sizes, int n_in,
                              void* d_out, int out_size, void* d_ws, size_t ws_size,
                              hipStream_t stream) {
    const float* x     = (const float*)d_in[0];
    const float* Wq    = (const float*)d_in[1];
    const float* bq    = (const float*)d_in[2];
    const float* Wk    = (const float*)d_in[3];
    const float* bk    = (const float*)d_in[4];
    const float* Wv    = (const float*)d_in[5];
    const float* bv    = (const float*)d_in[6];
    const float* gamma = (const float*)d_in[7];
    float* out = (float*)d_out;

    constexpr int Bn = 2, C = 128, N = 4096;
    __bf16* qT  = (__bf16*)d_ws;
    __bf16* kT  = qT + (size_t)Bn * N * C;
    __bf16* vT2 = kT + (size_t)Bn * N * C;

    proj_kernel<<<dim3(N / 32, 3, Bn), 256, 0, stream>>>(
        x, Wq, bq, Wk, bk, Wv, bv, qT, kT, vT2);
    flash_kernel<<<dim3(N / 16, Bn), 512, 0, stream>>>(
        qT, kT, vT2, x, gamma, out);
}

// Round 5
// 157.107 us; speedup vs baseline: 4.7207x; 1.2908x over previous
//
#include <hip/hip_runtime.h>
#include <hip/hip_bf16.h>

typedef __bf16 bf16x8 __attribute__((ext_vector_type(8)));
typedef __bf16 bf16x4 __attribute__((ext_vector_type(4)));
typedef float  floatx4 __attribute__((ext_vector_type(4)));

// B=2, C=128, N=4096. fp32 in/out.
// ws: qT[b][n][c] | kT[b][m][c] | vT2[b][c][m] (bf16, 2MB ea) | Whi[3][128][128] |
//     Wlo[3][128][128] (bf16) | [if fits] Opart[s][b][n][c] bf16 8.4MB | ml[s][b][n][2] f32

// ---------------- prep: W -> hi/lo bf16 split ----------------
__global__ __launch_bounds__(256) void prep_w(
    const float* __restrict__ Wq, const float* __restrict__ Wk,
    const float* __restrict__ Wv, __bf16* __restrict__ Whi, __bf16* __restrict__ Wlo)
{
    const int idx = blockIdx.x * 256 + threadIdx.x;   // < 3*16384
    const int which = idx >> 14, rem = idx & 16383;
    const float w = (which == 0 ? Wq : which == 1 ? Wk : Wv)[rem];
    const __bf16 hi = (__bf16)w;
    Whi[idx] = hi;
    Wlo[idx] = (__bf16)(w - (float)hi);
}

// ---------------- proj: MFMA QKV (hi/lo W), fp32 x staged->bf16 ----------------
// grid (N/64, B), block 256 = 4 waves; wave wv owns 16 n.
__global__ __launch_bounds__(256) void proj_kernel(
    const float* __restrict__ x, const __bf16* __restrict__ Whi,
    const __bf16* __restrict__ Wlo,
    const float* __restrict__ bq, const float* __restrict__ bk,
    const float* __restrict__ bv,
    __bf16* __restrict__ qT, __bf16* __restrict__ kT, __bf16* __restrict__ vT2)
{
    constexpr int C = 128, N = 4096;
    const int b = blockIdx.y, n0 = blockIdx.x * 64;
    const int tid = threadIdx.x;
    const int wv = tid >> 6, lane = tid & 63, l15 = lane & 15, quad = lane >> 4;

    __shared__ __bf16 xt[64][136];    // xt[n-local][c]
    __shared__ __bf16 v_lds[128][72]; // v transpose tile [c][n-local]

    #pragma unroll
    for (int rep = 0; rep < 8; ++rep) {            // 2048 float4 loads
        const int j = tid + rep * 256;
        const int c = j >> 4, nl = (j & 15) * 4;
        const float4 xv = *(const float4*)(x + (size_t)(b * C + c) * N + n0 + nl);
        xt[nl + 0][c] = (__bf16)xv.x; xt[nl + 1][c] = (__bf16)xv.y;
        xt[nl + 2][c] = (__bf16)xv.z; xt[nl + 3][c] = (__bf16)xv.w;
    }
    __syncthreads();

    bf16x8 xb[4];
    #pragma unroll
    for (int kk = 0; kk < 4; ++kk)
        xb[kk] = *(bf16x8*)(&xt[wv * 16 + l15][kk * 32 + quad * 8]);

    const int n = n0 + wv * 16 + l15;
    for (int which = 0; which < 3; ++which) {
        floatx4 acc[8];
        const floatx4 fz = {0.f, 0.f, 0.f, 0.f};
        #pragma unroll
        for (int t = 0; t < 8; ++t) acc[t] = fz;
        #pragma unroll
        for (int kk = 0; kk < 4; ++kk)
            #pragma unroll
            for (int ct = 0; ct < 8; ++ct) {
                const size_t wo = (size_t)which * 16384 + (ct * 16 + l15) * 128 + kk * 32 + quad * 8;
                const bf16x8 ahi = *(const bf16x8*)(Whi + wo);
                const bf16x8 alo = *(const bf16x8*)(Wlo + wo);
                acc[ct] = __builtin_amdgcn_mfma_f32_16x16x32_bf16(ahi, xb[kk], acc[ct], 0, 0, 0);
                acc[ct] = __builtin_amdgcn_mfma_f32_16x16x32_bf16(alo, xb[kk], acc[ct], 0, 0, 0);
            }
        const float* bias = (which == 0) ? bq : (which == 1) ? bk : bv;
        if (which < 2) {
            __bf16* dst = (which == 0) ? qT : kT;
            #pragma unroll
            for (int ct = 0; ct < 8; ++ct) {
                const float4 b4 = *(const float4*)(bias + ct * 16 + quad * 4);
                bf16x4 o;
                #pragma unroll
                for (int r = 0; r < 4; ++r) o[r] = (__bf16)(acc[ct][r] + (&b4.x)[r]);
                *(bf16x4*)(dst + (size_t)(b * N + n) * C + ct * 16 + quad * 4) = o;
            }
        } else {
            #pragma unroll
            for (int ct = 0; ct < 8; ++ct) {
                const float4 b4 = *(const float4*)(bias + ct * 16 + quad * 4);
                #pragma unroll
                for (int r = 0; r < 4; ++r)
                    v_lds[ct * 16 + quad * 4 + r][wv * 16 + l15] = (__bf16)(acc[ct][r] + (&b4.x)[r]);
            }
        }
    }
    __syncthreads();
    #pragma unroll
    for (int rep = 0; rep < 4; ++rep) {            // 1024 bf16x8 stores
        const int j = tid + rep * 256;
        const int c = j >> 3, nc = (j & 7) * 8;
        *(bf16x8*)(vT2 + (size_t)(b * C + c) * N + n0 + nc) = *(bf16x8*)(&v_lds[c][nc]);
    }
}

// ---------------- flash: classic tiling, K/V shared via LDS ----------------
// block 512 = 8 waves; wave wv owns n-sub-tile wv*16 within the block's 128 n.
// grid flat 32*NSPLIT*B, XCD-pinned: batch = (bid&7)>>2 so each XCD's L2 holds
// one batch's K+V (4MB). NSPLIT=4 writes bf16 partials; NSPLIT=1 writes final.
template <int NSPLIT, bool PARTIAL>
__global__ __launch_bounds__(512, 2) void flash_kernel(
    const __bf16* __restrict__ qT, const __bf16* __restrict__ kT,
    const __bf16* __restrict__ vT2, const float* __restrict__ x,
    const float* __restrict__ gamma_p, __bf16* __restrict__ Opart,
    float* __restrict__ ml, float* __restrict__ out)
{
    constexpr int C = 128, N = 4096, Bn = 2;
    const int bid = blockIdx.x;
    const int r7 = bid & 7;
    const int b = r7 >> 2;
    const int rest = (bid >> 3) * 4 + (r7 & 3);    // 0..32*NSPLIT-1
    const int nt = rest & 31, split = rest >> 5;
    const int n0 = nt * 128;
    const int tid = threadIdx.x;
    const int wv = tid >> 6, lane = tid & 63, l15 = lane & 15, quad = lane >> 4;

    __shared__ __bf16 k_s[64][136];
    __shared__ __bf16 v_s[128][72];
    __shared__ __bf16 p_s[8][16][72];

    const int n = n0 + wv * 16 + l15;
    bf16x8 qb[4];
    #pragma unroll
    for (int kk = 0; kk < 4; ++kk)
        qb[kk] = *(const bf16x8*)(qT + (size_t)(b * N + n) * C + kk * 32 + quad * 8);

    float m_i = -1e30f, l_i = 0.f;
    floatx4 Oacc[8];
    const floatx4 fz = {0.f, 0.f, 0.f, 0.f};
    #pragma unroll
    for (int t = 0; t < 8; ++t) Oacc[t] = fz;

    constexpr int mlen = N / NSPLIT;
    const int mbeg = split * mlen;
    for (int it = 0; it < mlen / 64; ++it) {
        const int m0 = mbeg + it * 64;
        __syncthreads();
        #pragma unroll
        for (int rep = 0; rep < 2; ++rep) {        // K: 64x16 chunks
            const int j = tid + rep * 512;
            const int row = j >> 4, c8 = (j & 15) * 8;
            *(bf16x8*)(&k_s[row][c8]) =
                *(const bf16x8*)(kT + (size_t)(b * N + m0 + row) * C + c8);
        }
        #pragma unroll
        for (int rep = 0; rep < 2; ++rep) {        // V: 128x8 chunks
            const int j = tid + rep * 512;
            const int c = j >> 3, mc = (j & 7) * 8;
            *(bf16x8*)(&v_s[c][mc]) =
                *(const bf16x8*)(vT2 + (size_t)(b * C + c) * N + m0 + mc);
        }
        __syncthreads();

        floatx4 S[4];
        #pragma unroll
        for (int ct = 0; ct < 4; ++ct) S[ct] = fz;
        #pragma unroll
        for (int kk = 0; kk < 4; ++kk)
            #pragma unroll
            for (int ct = 0; ct < 4; ++ct) {
                const bf16x8 a = *(bf16x8*)(&k_s[ct * 16 + l15][kk * 32 + quad * 8]);
                S[ct] = __builtin_amdgcn_mfma_f32_16x16x32_bf16(a, qb[kk], S[ct], 0, 0, 0);
            }

        float rmax = -1e30f;
        #pragma unroll
        for (int ct = 0; ct < 4; ++ct)
            #pragma unroll
            for (int r = 0; r < 4; ++r) {
                const float v = S[ct][r] * 1.3f;
                S[ct][r] = v;
                rmax = fmaxf(rmax, v);
            }
        rmax = fmaxf(rmax, __shfl_xor(rmax, 16, 64));
        rmax = fmaxf(rmax, __shfl_xor(rmax, 32, 64));

        const float mn = fmaxf(m_i, rmax);
        const float alpha = __expf(m_i - mn);
        m_i = mn;

        float rsum = 0.f;
        #pragma unroll
        for (int ct = 0; ct < 4; ++ct)
            #pragma unroll
            for (int r = 0; r < 4; ++r) {
                const float p = __expf(S[ct][r] - m_i);
                S[ct][r] = p;
                rsum += p;
            }
        rsum += __shfl_xor(rsum, 16, 64);
        rsum += __shfl_xor(rsum, 32, 64);
        l_i = l_i * alpha + rsum;

        #pragma unroll
        for (int t = 0; t < 8; ++t)
            #pragma unroll
            for (int r = 0; r < 4; ++r) Oacc[t][r] *= alpha;

        #pragma unroll
        for (int ct = 0; ct < 4; ++ct) {
            bf16x4 pk;
            #pragma unroll
            for (int r = 0; r < 4; ++r) pk[r] = (__bf16)S[ct][r];
            *(bf16x4*)(&p_s[wv][l15][ct * 16 + quad * 4]) = pk;
        }

        #pragma unroll
        for (int kk = 0; kk < 2; ++kk) {
            const bf16x8 pb = *(bf16x8*)(&p_s[wv][l15][kk * 32 + quad * 8]);
            #pragma unroll
            for (int ct = 0; ct < 8; ++ct) {
                const bf16x8 a = *(bf16x8*)(&v_s[ct * 16 + l15][kk * 32 + quad * 8]);
                Oacc[ct] = __builtin_amdgcn_mfma_f32_16x16x32_bf16(a, pb, Oacc[ct], 0, 0, 0);
            }
        }
    }

    if (PARTIAL) {
        __bf16* Op = Opart + (((size_t)split * Bn + b) * N + n) * C;
        #pragma unroll
        for (int ct = 0; ct < 8; ++ct) {
            bf16x4 o;
            #pragma unroll
            for (int r = 0; r < 4; ++r) o[r] = (__bf16)Oacc[ct][r];
            *(bf16x4*)(Op + ct * 16 + quad * 4) = o;
        }
        if (quad == 0) {
            float* mlp = ml + (((size_t)split * Bn + b) * N + n) * 2;
            mlp[0] = m_i; mlp[1] = l_i;
        }
    } else {
        const float sc = 1.f / l_i;
        const float gamma = gamma_p[0];
        #pragma unroll
        for (int ct = 0; ct < 8; ++ct)
            #pragma unroll
            for (int r = 0; r < 4; ++r) {
                const int c = ct * 16 + quad * 4 + r;
                const size_t idx = ((size_t)b * C + c) * N + n;
                out[idx] = x[idx] + gamma * Oacc[ct][r] * sc;
            }
    }
}

// ---------------- combine (NSPLIT=4): merge partials + epilogue ----------------
// grid (N/64, B), block 256.
__global__ __launch_bounds__(256) void combine_kernel(
    const __bf16* __restrict__ Opart, const float* __restrict__ ml,
    const float* __restrict__ x, const float* __restrict__ gamma_p,
    float* __restrict__ out)
{
    constexpr int C = 128, N = 4096, Bn = 2, S = 4;
    const int b = blockIdx.y, n0 = blockIdx.x * 64;
    const int tid = threadIdx.x;
    __shared__ float cf[S][64];
    __shared__ float ot[128][65];

    if (tid < 64) {
        const int n = n0 + tid;
        float ms[S], ls[S];
        #pragma unroll
        for (int s = 0; s < S; ++s) {
            const float* mlp = ml + (((size_t)s * Bn + b) * N + n) * 2;
            ms[s] = mlp[0]; ls[s] = mlp[1];
        }
        float M = -1e30f;
        #pragma unroll
        for (int s = 0; s < S; ++s) M = fmaxf(M, ms[s]);
        float L = 0.f, e[S];
        #pragma unroll
        for (int s = 0; s < S; ++s) { e[s] = __expf(ms[s] - M); L += e[s] * ls[s]; }
        const float inv = 1.f / L;
        #pragma unroll
        for (int s = 0; s < S; ++s) cf[s][tid] = e[s] * inv;
    }
    __syncthreads();

    #pragma unroll
    for (int rep = 0; rep < 4; ++rep) {            // 64 n x 16 c-chunks
        const int j = tid + rep * 256;
        const int nl = j >> 4, c8 = (j & 15) * 8;
        float acc[8] = {0,0,0,0,0,0,0,0};
        #pragma unroll
        for (int s = 0; s < S; ++s) {
            const float c0 = cf[s][nl];
            const bf16x8 ov = *(const bf16x8*)(Opart + (((size_t)s * Bn + b) * N + n0 + nl) * C + c8);
            #pragma unroll
            for (int t = 0; t < 8; ++t) acc[t] += c0 * (float)ov[t];
        }
        #pragma unroll
        for (int t = 0; t < 8; ++t) ot[c8 + t][nl] = acc[t];
    }
    __syncthreads();

    const int nl = tid & 63, cg = tid >> 6;
    const float gamma = gamma_p[0];
    for (int c2 = cg; c2 < 128; c2 += 4) {
        const size_t idx = ((size_t)b * C + c2) * N + n0 + nl;
        out[idx] = x[idx] + gamma * ot[c2][nl];
    }
}

extern "C" void kernel_launch(void* const* d_in, const int* in_sizes, int n_in,
                              void* d_out, int out_size, void* d_ws, size_t ws_size,
                              hipStream_t stream) {
    const float* x     = (const float*)d_in[0];
    const float* Wq    = (const float*)d_in[1];
    const float* bq    = (const float*)d_in[2];
    const float* Wk    = (const float*)d_in[3];
    const float* bk    = (const float*)d_in[4];
    const float* Wv    = (const float*)d_in[5];
    const float* bv    = (const float*)d_in[6];
    const float* gamma = (const float*)d_in[7];
    float* out = (float*)d_out;

    constexpr int Bn = 2, C = 128, N = 4096;
    constexpr size_t QKV = (size_t)Bn * N * C;     // elements
    __bf16* qT  = (__bf16*)d_ws;
    __bf16* kT  = qT + QKV;
    __bf16* vT2 = kT + QKV;
    __bf16* Whi = vT2 + QKV;
    __bf16* Wlo = Whi + 3 * 16384;
    __bf16* Opart = Wlo + 3 * 16384;               // 4*Bn*N*C bf16
    float*  ml = (float*)(Opart + (size_t)4 * Bn * N * C);
    const size_t need = (char*)(ml + (size_t)4 * Bn * N * 2) - (char*)d_ws;

    prep_w<<<192, 256, 0, stream>>>(Wq, Wk, Wv, Whi, Wlo);
    proj_kernel<<<dim3(N / 64, Bn), 256, 0, stream>>>(
        x, Whi, Wlo, bq, bk, bv, qT, kT, vT2);

    if (ws_size >= need) {
        flash_kernel<4, true><<<32 * 4 * Bn, 512, 0, stream>>>(
            qT, kT, vT2, x, gamma, Opart, ml, out);
        combine_kernel<<<dim3(N / 64, Bn), 256, 0, stream>>>(
            Opart, ml, x, gamma, out);
    } else {
        flash_kernel<1, false><<<32 * 1 * Bn, 512, 0, stream>>>(
            qT, kT, vT2, x, gamma, nullptr, nullptr, out);
    }
}

// Round 7
// 128.183 us; speedup vs baseline: 5.7859x; 1.2256x over previous
//
#include <hip/hip_runtime.h>
#include <hip/hip_bf16.h>

typedef __bf16 bf16x8 __attribute__((ext_vector_type(8)));
typedef __bf16 bf16x4 __attribute__((ext_vector_type(4)));
typedef float  floatx4 __attribute__((ext_vector_type(4)));

// B=2, C=128, N=4096. fp32 in/out.
// ws: qT[b][n][c] | kT[b][m][c] | vT2[b][c][m] (bf16, 2MB ea)
//     | Opart[s][b][n][c] bf16 8.4MB | ml[s][b][n][2] f32  (NSPLIT=4 path)
// Flash softmax runs base-2: S_f32 * (1.3*log2e), then exp2f. q/k stored UNSCALED.

#define QSCALE 1.8755035f   // 1.3 * log2(e)

// ---------------- proj: MFMA QKV, W AND x hi/lo split (3-term) ----------------
// grid (N/32, 3, B), block 128 = 2 waves; wave owns 16 n.
// acc = Whi*xhi + Wlo*xhi + Whi*xlo  (err ~ Wlo*xlo ~ 2^-17 rel)
__global__ __launch_bounds__(128) void proj_kernel(
    const float* __restrict__ x,
    const float* __restrict__ Wq, const float* __restrict__ bq,
    const float* __restrict__ Wk, const float* __restrict__ bk,
    const float* __restrict__ Wv, const float* __restrict__ bv,
    __bf16* __restrict__ qT, __bf16* __restrict__ kT, __bf16* __restrict__ vT2)
{
    constexpr int C = 128, N = 4096;
    const int b = blockIdx.z, which = blockIdx.y, n0 = blockIdx.x * 32;
    const int tid = threadIdx.x;
    const int wv = tid >> 6, lane = tid & 63, l15 = lane & 15, quad = lane >> 4;
    const float* W    = (which == 0) ? Wq : (which == 1) ? Wk : Wv;
    const float* bias = (which == 0) ? bq : (which == 1) ? bk : bv;

    __shared__ __bf16 xhi[32][136];    // [n-local][c]
    __shared__ __bf16 xlo[32][136];
    __shared__ __bf16 v_lds[128][40];  // v transpose tile [c][n-local]

    #pragma unroll
    for (int rep = 0; rep < 8; ++rep) {           // 1024 float4 loads
        const int j = tid + rep * 128;
        const int c = j >> 3, nl4 = (j & 7) * 4;
        const float4 xv = *(const float4*)(x + (size_t)(b * C + c) * N + n0 + nl4);
        #pragma unroll
        for (int r = 0; r < 4; ++r) {
            const float v = (&xv.x)[r];
            const __bf16 h = (__bf16)v;
            xhi[nl4 + r][c] = h;
            xlo[nl4 + r][c] = (__bf16)(v - (float)h);
        }
    }
    __syncthreads();

    bf16x8 xbh[4], xbl[4];
    #pragma unroll
    for (int kk = 0; kk < 4; ++kk) {
        xbh[kk] = *(bf16x8*)(&xhi[wv * 16 + l15][kk * 32 + quad * 8]);
        xbl[kk] = *(bf16x8*)(&xlo[wv * 16 + l15][kk * 32 + quad * 8]);
    }

    floatx4 acc[8];
    const floatx4 fz = {0.f, 0.f, 0.f, 0.f};
    #pragma unroll
    for (int t = 0; t < 8; ++t) acc[t] = fz;

    #pragma unroll
    for (int kk = 0; kk < 4; ++kk)
        #pragma unroll
        for (int ct = 0; ct < 8; ++ct) {
            const float* wp = W + (size_t)(ct * 16 + l15) * C + kk * 32 + quad * 8;
            const float4 w0 = *(const float4*)wp;
            const float4 w1 = *(const float4*)(wp + 4);
            bf16x8 ahi, alo;
            #pragma unroll
            for (int r = 0; r < 4; ++r) {
                const float v0 = (&w0.x)[r]; const __bf16 h0 = (__bf16)v0;
                ahi[r] = h0; alo[r] = (__bf16)(v0 - (float)h0);
                const float v1 = (&w1.x)[r]; const __bf16 h1 = (__bf16)v1;
                ahi[4 + r] = h1; alo[4 + r] = (__bf16)(v1 - (float)h1);
            }
            acc[ct] = __builtin_amdgcn_mfma_f32_16x16x32_bf16(ahi, xbh[kk], acc[ct], 0, 0, 0);
            acc[ct] = __builtin_amdgcn_mfma_f32_16x16x32_bf16(alo, xbh[kk], acc[ct], 0, 0, 0);
            acc[ct] = __builtin_amdgcn_mfma_f32_16x16x32_bf16(ahi, xbl[kk], acc[ct], 0, 0, 0);
        }

    const int n = n0 + wv * 16 + l15;
    if (which < 2) {
        __bf16* dst = (which == 0) ? qT : kT;
        #pragma unroll
        for (int ct = 0; ct < 8; ++ct) {
            const float4 b4 = *(const float4*)(bias + ct * 16 + quad * 4);
            bf16x4 o;
            #pragma unroll
            for (int r = 0; r < 4; ++r) o[r] = (__bf16)(acc[ct][r] + (&b4.x)[r]);
            *(bf16x4*)(dst + (size_t)(b * N + n) * C + ct * 16 + quad * 4) = o;
        }
    } else {
        #pragma unroll
        for (int ct = 0; ct < 8; ++ct) {
            const float4 b4 = *(const float4*)(bias + ct * 16 + quad * 4);
            #pragma unroll
            for (int r = 0; r < 4; ++r)
                v_lds[ct * 16 + quad * 4 + r][wv * 16 + l15] = (__bf16)(acc[ct][r] + (&b4.x)[r]);
        }
        __syncthreads();
        #pragma unroll
        for (int rep = 0; rep < 4; ++rep) {       // 512 bf16x8 stores
            const int j = tid + rep * 128;
            const int c = j >> 2, m8 = (j & 3) * 8;
            *(bf16x8*)(vT2 + (size_t)(b * C + c) * N + n0 + m8) = *(bf16x8*)(&v_lds[c][m8]);
        }
    }
}

// ---------------- flash: 64-n tiles, 2 blocks/CU, register-prefetch dbuf ----------------
// block 256 = 4 waves; wave owns 16 n. grid flat 64*NSPLIT*B, XCD-pinned on batch.
template <int NSPLIT, bool PARTIAL>
__global__ __launch_bounds__(256, 2) void flash_kernel(
    const __bf16* __restrict__ qT, const __bf16* __restrict__ kT,
    const __bf16* __restrict__ vT2, const float* __restrict__ x,
    const float* __restrict__ gamma_p, __bf16* __restrict__ Opart,
    float* __restrict__ ml, float* __restrict__ out)
{
    constexpr int C = 128, N = 4096, Bn = 2;
    const int bid = blockIdx.x;
    const int r7 = bid & 7;
    const int b = r7 >> 2;                         // XCD-pinned batch
    const int rest = (bid >> 3) * 4 + (r7 & 3);    // 0 .. 64*NSPLIT-1
    const int nt = rest & 63, split = rest >> 6;
    const int n0 = nt * 64;
    const int tid = threadIdx.x;
    const int wv = tid >> 6, lane = tid & 63, l15 = lane & 15, quad = lane >> 4;

    __shared__ __bf16 k_s[64][136];
    __shared__ __bf16 v_s[128][72];
    __shared__ __bf16 p_s[4][16][72];

    const int n = n0 + wv * 16 + l15;
    bf16x8 qb[4];
    #pragma unroll
    for (int kk = 0; kk < 4; ++kk)
        qb[kk] = *(const bf16x8*)(qT + (size_t)(b * N + n) * C + kk * 32 + quad * 8);

    float m_i = -3.0e38f, l_i = 0.f;
    floatx4 Oacc[8];
    const floatx4 fz = {0.f, 0.f, 0.f, 0.f};
    #pragma unroll
    for (int t = 0; t < 8; ++t) Oacc[t] = fz;

    const __bf16* kB = kT  + (size_t)b * N * C;
    const __bf16* vB = vT2 + (size_t)b * C * N;
    constexpr int ITERS = (N / NSPLIT) / 64;
    const int mbeg = split * (N / NSPLIT);

    // prefetch tile 0 into registers
    bf16x8 kpre[4], vpre[4];
    #pragma unroll
    for (int rep = 0; rep < 4; ++rep) {
        const int kj = tid + rep * 256;
        kpre[rep] = *(const bf16x8*)(kB + (size_t)(mbeg + (kj >> 4)) * C + (kj & 15) * 8);
        const int vj = tid + rep * 256;
        vpre[rep] = *(const bf16x8*)(vB + (size_t)(vj >> 3) * N + mbeg + (vj & 7) * 8);
    }

    for (int it = 0; it < ITERS; ++it) {
        __syncthreads();                           // LDS consumers of prev tile done
        #pragma unroll
        for (int rep = 0; rep < 4; ++rep) {
            const int kj = tid + rep * 256;
            *(bf16x8*)(&k_s[kj >> 4][(kj & 15) * 8]) = kpre[rep];
            const int vj = tid + rep * 256;
            *(bf16x8*)(&v_s[vj >> 3][(vj & 7) * 8]) = vpre[rep];
        }
        __syncthreads();                           // LDS ready

        if (it + 1 < ITERS) {                      // issue next-tile loads now;
            const int m1 = mbeg + (it + 1) * 64;   // consumed after next barrier
            #pragma unroll
            for (int rep = 0; rep < 4; ++rep) {
                const int kj = tid + rep * 256;
                kpre[rep] = *(const bf16x8*)(kB + (size_t)(m1 + (kj >> 4)) * C + (kj & 15) * 8);
                const int vj = tid + rep * 256;
                vpre[rep] = *(const bf16x8*)(vB + (size_t)(vj >> 3) * N + m1 + (vj & 7) * 8);
            }
        }

        // S^T = K Q^T, then scale to base-2 domain in fp32
        floatx4 S[4];
        #pragma unroll
        for (int ct = 0; ct < 4; ++ct) S[ct] = fz;
        #pragma unroll
        for (int kk = 0; kk < 4; ++kk)
            #pragma unroll
            for (int ct = 0; ct < 4; ++ct) {
                const bf16x8 a = *(bf16x8*)(&k_s[ct * 16 + l15][kk * 32 + quad * 8]);
                S[ct] = __builtin_amdgcn_mfma_f32_16x16x32_bf16(a, qb[kk], S[ct], 0, 0, 0);
            }

        float rmax = -3.0e38f;
        #pragma unroll
        for (int ct = 0; ct < 4; ++ct)
            #pragma unroll
            for (int r = 0; r < 4; ++r) {
                const float v = S[ct][r] * QSCALE;
                S[ct][r] = v;
                rmax = fmaxf(rmax, v);
            }
        rmax = fmaxf(rmax, __shfl_xor(rmax, 16, 64));
        rmax = fmaxf(rmax, __shfl_xor(rmax, 32, 64));

        const float mn = fmaxf(m_i, rmax);
        const float alpha = exp2f(m_i - mn);
        m_i = mn;

        float rsum = 0.f;
        #pragma unroll
        for (int ct = 0; ct < 4; ++ct)
            #pragma unroll
            for (int r = 0; r < 4; ++r) {
                const float p = exp2f(S[ct][r] - m_i);
                S[ct][r] = p;
                rsum += p;
            }
        rsum += __shfl_xor(rsum, 16, 64);
        rsum += __shfl_xor(rsum, 32, 64);
        l_i = l_i * alpha + rsum;

        #pragma unroll
        for (int t = 0; t < 8; ++t)
            #pragma unroll
            for (int r = 0; r < 4; ++r) Oacc[t][r] *= alpha;

        #pragma unroll
        for (int ct = 0; ct < 4; ++ct) {
            bf16x4 pk;
            #pragma unroll
            for (int r = 0; r < 4; ++r) pk[r] = (__bf16)S[ct][r];
            *(bf16x4*)(&p_s[wv][l15][ct * 16 + quad * 4]) = pk;
        }

        #pragma unroll
        for (int kk = 0; kk < 2; ++kk) {
            const bf16x8 pb = *(bf16x8*)(&p_s[wv][l15][kk * 32 + quad * 8]);
            #pragma unroll
            for (int ct = 0; ct < 8; ++ct) {
                const bf16x8 a = *(bf16x8*)(&v_s[ct * 16 + l15][kk * 32 + quad * 8]);
                Oacc[ct] = __builtin_amdgcn_mfma_f32_16x16x32_bf16(a, pb, Oacc[ct], 0, 0, 0);
            }
        }
    }

    if (PARTIAL) {
        __bf16* Op = Opart + (((size_t)split * Bn + b) * N + n) * C;
        #pragma unroll
        for (int ct = 0; ct < 8; ++ct) {
            bf16x4 o;
            #pragma unroll
            for (int r = 0; r < 4; ++r) o[r] = (__bf16)Oacc[ct][r];
            *(bf16x4*)(Op + ct * 16 + quad * 4) = o;
        }
        if (quad == 0) {
            float* mlp = ml + (((size_t)split * Bn + b) * N + n) * 2;
            mlp[0] = m_i; mlp[1] = l_i;
        }
    } else {
        const float sc = 1.f / l_i;
        const float gamma = gamma_p[0];
        #pragma unroll
        for (int ct = 0; ct < 8; ++ct)
            #pragma unroll
            for (int r = 0; r < 4; ++r) {
                const int c = ct * 16 + quad * 4 + r;
                const size_t idx = ((size_t)b * C + c) * N + n;
                out[idx] = x[idx] + gamma * Oacc[ct][r] * sc;
            }
    }
}

// ---------------- combine (NSPLIT=4): merge partials + epilogue ----------------
// grid (N/32, B), block 256. Base-2 merge (m,l are exp2-domain).
__global__ __launch_bounds__(256) void combine_kernel(
    const __bf16* __restrict__ Opart, const float* __restrict__ ml,
    const float* __restrict__ x, const float* __restrict__ gamma_p,
    float* __restrict__ out)
{
    constexpr int C = 128, N = 4096, Bn = 2, S = 4;
    const int b = blockIdx.y, n0 = blockIdx.x * 32;
    const int tid = threadIdx.x;
    __shared__ float cf[S][32];
    __shared__ float ot[32][132];     // ot[n-local][c]

    if (tid < 32) {
        const int n = n0 + tid;
        float ms[S], ls[S];
        #pragma unroll
        for (int s = 0; s < S; ++s) {
            const float* mlp = ml + (((size_t)s * Bn + b) * N + n) * 2;
            ms[s] = mlp[0]; ls[s] = mlp[1];
        }
        float M = -3.0e38f;
        #pragma unroll
        for (int s = 0; s < S; ++s) M = fmaxf(M, ms[s]);
        float L = 0.f, e[S];
        #pragma unroll
        for (int s = 0; s < S; ++s) { e[s] = exp2f(ms[s] - M); L += e[s] * ls[s]; }
        const float inv = 1.f / L;
        #pragma unroll
        for (int s = 0; s < S; ++s) cf[s][tid] = e[s] * inv;
    }
    __syncthreads();

    #pragma unroll
    for (int rep = 0; rep < 2; ++rep) {            // 32 n x 16 c-chunks
        const int j = tid + rep * 256;
        const int nl = j >> 4, c8 = (j & 15) * 8;
        float acc[8] = {0, 0, 0, 0, 0, 0, 0, 0};
        #pragma unroll
        for (int s = 0; s < S; ++s) {
            const float c0 = cf[s][nl];
            const bf16x8 ov = *(const bf16x8*)(Opart + (((size_t)s * Bn + b) * N + n0 + nl) * C + c8);
            #pragma unroll
            for (int t = 0; t < 8; ++t) acc[t] += c0 * (float)ov[t];
        }
        *(float4*)(&ot[nl][c8])     = *(float4*)(&acc[0]);
        *(float4*)(&ot[nl][c8 + 4]) = *(float4*)(&acc[4]);
    }
    __syncthreads();

    const int nl = tid & 31, cbase = tid >> 5;     // 8 c-groups
    const float gamma = gamma_p[0];
    #pragma unroll
    for (int k = 0; k < 16; ++k) {
        const int c = cbase * 16 + k;
        const size_t idx = ((size_t)b * C + c) * N + n0 + nl;
        out[idx] = x[idx] + gamma * ot[nl][c];
    }
}

extern "C" void kernel_launch(void* const* d_in, const int* in_sizes, int n_in,
                              void* d_out, int out_size, void* d_ws, size_t ws_size,
                              hipStream_t stream) {
    const float* x     = (const float*)d_in[0];
    const float* Wq    = (const float*)d_in[1];
    const float* bq    = (const float*)d_in[2];
    const float* Wk    = (const float*)d_in[3];
    const float* bk    = (const float*)d_in[4];
    const float* Wv    = (const float*)d_in[5];
    const float* bv    = (const float*)d_in[6];
    const float* gamma = (const float*)d_in[7];
    float* out = (float*)d_out;

    constexpr int Bn = 2, C = 128, N = 4096;
    constexpr size_t QKV = (size_t)Bn * N * C;     // elements per tensor
    __bf16* qT    = (__bf16*)d_ws;
    __bf16* kT    = qT + QKV;
    __bf16* vT2   = kT + QKV;
    __bf16* Opart = vT2 + QKV;                     // 4*Bn*N*C bf16
    float*  ml    = (float*)(Opart + (size_t)4 * Bn * N * C);
    const size_t need = (char*)(ml + (size_t)4 * Bn * N * 2) - (char*)d_ws;

    proj_kernel<<<dim3(N / 32, 3, Bn), 128, 0, stream>>>(
        x, Wq, bq, Wk, bk, Wv, bv, qT, kT, vT2);

    if (ws_size >= need) {
        flash_kernel<4, true><<<64 * 4 * Bn, 256, 0, stream>>>(
            qT, kT, vT2, x, gamma, Opart, ml, out);
        combine_kernel<<<dim3(N / 32, Bn), 256, 0, stream>>>(
            Opart, ml, x, gamma, out);
    } else {
        flash_kernel<1, false><<<64 * 1 * Bn, 256, 0, stream>>>(
            qT, kT, vT2, x, gamma, nullptr, nullptr, out);
    }
}

// Round 8
// 125.735 us; speedup vs baseline: 5.8985x; 1.0195x over previous
//
#include <hip/hip_runtime.h>
#include <hip/hip_bf16.h>

typedef __bf16 bf16x8 __attribute__((ext_vector_type(8)));
typedef __bf16 bf16x4 __attribute__((ext_vector_type(4)));
typedef float  floatx4 __attribute__((ext_vector_type(4)));

// B=2, C=128, N=4096. fp32 in/out.
// ws: qT[b][n][c] | kT[b][m][c] | vT2[b][c][m] (bf16, 2MB ea)
//     | Opart[s][b][n][c] bf16 | ml[s][b][n][2] f32   (s = NSPLIT)
// Flash softmax runs base-2: S_f32 * (1.3*log2e), then exp2f. q/k stored UNSCALED.

#define QSCALE 1.8755035f   // 1.3 * log2(e)

// ---------------- proj: MFMA QKV, W AND x hi/lo split (3-term) ----------------
// grid (N/32, 3, B), block 128 = 2 waves; wave owns 16 n.  (known-good, R7)
__global__ __launch_bounds__(128) void proj_kernel(
    const float* __restrict__ x,
    const float* __restrict__ Wq, const float* __restrict__ bq,
    const float* __restrict__ Wk, const float* __restrict__ bk,
    const float* __restrict__ Wv, const float* __restrict__ bv,
    __bf16* __restrict__ qT, __bf16* __restrict__ kT, __bf16* __restrict__ vT2)
{
    constexpr int C = 128, N = 4096;
    const int b = blockIdx.z, which = blockIdx.y, n0 = blockIdx.x * 32;
    const int tid = threadIdx.x;
    const int wv = tid >> 6, lane = tid & 63, l15 = lane & 15, quad = lane >> 4;
    const float* W    = (which == 0) ? Wq : (which == 1) ? Wk : Wv;
    const float* bias = (which == 0) ? bq : (which == 1) ? bk : bv;

    __shared__ __bf16 xhi[32][136];
    __shared__ __bf16 xlo[32][136];
    __shared__ __bf16 v_lds[128][40];

    #pragma unroll
    for (int rep = 0; rep < 8; ++rep) {
        const int j = tid + rep * 128;
        const int c = j >> 3, nl4 = (j & 7) * 4;
        const float4 xv = *(const float4*)(x + (size_t)(b * C + c) * N + n0 + nl4);
        #pragma unroll
        for (int r = 0; r < 4; ++r) {
            const float v = (&xv.x)[r];
            const __bf16 h = (__bf16)v;
            xhi[nl4 + r][c] = h;
            xlo[nl4 + r][c] = (__bf16)(v - (float)h);
        }
    }
    __syncthreads();

    bf16x8 xbh[4], xbl[4];
    #pragma unroll
    for (int kk = 0; kk < 4; ++kk) {
        xbh[kk] = *(bf16x8*)(&xhi[wv * 16 + l15][kk * 32 + quad * 8]);
        xbl[kk] = *(bf16x8*)(&xlo[wv * 16 + l15][kk * 32 + quad * 8]);
    }

    floatx4 acc[8];
    const floatx4 fz = {0.f, 0.f, 0.f, 0.f};
    #pragma unroll
    for (int t = 0; t < 8; ++t) acc[t] = fz;

    #pragma unroll
    for (int kk = 0; kk < 4; ++kk)
        #pragma unroll
        for (int ct = 0; ct < 8; ++ct) {
            const float* wp = W + (size_t)(ct * 16 + l15) * C + kk * 32 + quad * 8;
            const float4 w0 = *(const float4*)wp;
            const float4 w1 = *(const float4*)(wp + 4);
            bf16x8 ahi, alo;
            #pragma unroll
            for (int r = 0; r < 4; ++r) {
                const float v0 = (&w0.x)[r]; const __bf16 h0 = (__bf16)v0;
                ahi[r] = h0; alo[r] = (__bf16)(v0 - (float)h0);
                const float v1 = (&w1.x)[r]; const __bf16 h1 = (__bf16)v1;
                ahi[4 + r] = h1; alo[4 + r] = (__bf16)(v1 - (float)h1);
            }
            acc[ct] = __builtin_amdgcn_mfma_f32_16x16x32_bf16(ahi, xbh[kk], acc[ct], 0, 0, 0);
            acc[ct] = __builtin_amdgcn_mfma_f32_16x16x32_bf16(alo, xbh[kk], acc[ct], 0, 0, 0);
            acc[ct] = __builtin_amdgcn_mfma_f32_16x16x32_bf16(ahi, xbl[kk], acc[ct], 0, 0, 0);
        }

    const int n = n0 + wv * 16 + l15;
    if (which < 2) {
        __bf16* dst = (which == 0) ? qT : kT;
        #pragma unroll
        for (int ct = 0; ct < 8; ++ct) {
            const float4 b4 = *(const float4*)(bias + ct * 16 + quad * 4);
            bf16x4 o;
            #pragma unroll
            for (int r = 0; r < 4; ++r) o[r] = (__bf16)(acc[ct][r] + (&b4.x)[r]);
            *(bf16x4*)(dst + (size_t)(b * N + n) * C + ct * 16 + quad * 4) = o;
        }
    } else {
        #pragma unroll
        for (int ct = 0; ct < 8; ++ct) {
            const float4 b4 = *(const float4*)(bias + ct * 16 + quad * 4);
            #pragma unroll
            for (int r = 0; r < 4; ++r)
                v_lds[ct * 16 + quad * 4 + r][wv * 16 + l15] = (__bf16)(acc[ct][r] + (&b4.x)[r]);
        }
        __syncthreads();
        #pragma unroll
        for (int rep = 0; rep < 4; ++rep) {
            const int j = tid + rep * 128;
            const int c = j >> 2, m8 = (j & 3) * 8;
            *(bf16x8*)(vT2 + (size_t)(b * C + c) * N + n0 + m8) = *(bf16x8*)(&v_lds[c][m8]);
        }
    }
}

// ---------------- flash: 128-n tiles, wave owns 32 n (2 B-fragments) ----------------
// block 256 = 4 waves. Each K/V A-fragment LDS read feeds 2 MFMAs.
// grid flat 32*NSPLIT*B, XCD-pinned on batch via bid&7.
template <int NSPLIT, bool PARTIAL>
__global__ __launch_bounds__(256, 2) void flash_kernel(
    const __bf16* __restrict__ qT, const __bf16* __restrict__ kT,
    const __bf16* __restrict__ vT2, const float* __restrict__ x,
    const float* __restrict__ gamma_p, __bf16* __restrict__ Opart,
    float* __restrict__ ml, float* __restrict__ out)
{
    constexpr int C = 128, N = 4096, Bn = 2;
    const int bid = blockIdx.x;
    const int r7 = bid & 7;
    const int b = r7 >> 2;                         // XCD-pinned batch
    const int rest = (bid >> 3) * 4 + (r7 & 3);    // 0 .. 32*NSPLIT-1
    const int nt = rest / NSPLIT, split = rest % NSPLIT;
    const int n0 = nt * 128;
    const int tid = threadIdx.x;
    const int wv = tid >> 6, lane = tid & 63, l15 = lane & 15, quad = lane >> 4;

    __shared__ __bf16 k_s[64][136];
    __shared__ __bf16 v_s[128][72];
    __shared__ __bf16 p_s[4][32][72];              // per-wave P^T [n-local 32][m-local]

    const int nA = n0 + wv * 32 + l15;             // col set A; B = +16
    bf16x8 qbA[4], qbB[4];
    #pragma unroll
    for (int kk = 0; kk < 4; ++kk) {
        qbA[kk] = *(const bf16x8*)(qT + (size_t)(b * N + nA) * C + kk * 32 + quad * 8);
        qbB[kk] = *(const bf16x8*)(qT + (size_t)(b * N + nA + 16) * C + kk * 32 + quad * 8);
    }

    float mA = -3.0e38f, lA = 0.f, mB = -3.0e38f, lB = 0.f;
    floatx4 OA[8], OB[8];
    const floatx4 fz = {0.f, 0.f, 0.f, 0.f};
    #pragma unroll
    for (int t = 0; t < 8; ++t) { OA[t] = fz; OB[t] = fz; }

    const __bf16* kB = kT  + (size_t)b * N * C;
    const __bf16* vB = vT2 + (size_t)b * C * N;
    constexpr int ITERS = (N / NSPLIT) / 64;
    const int mbeg = split * (N / NSPLIT);

    bf16x8 kpre[4], vpre[4];
    #pragma unroll
    for (int rep = 0; rep < 4; ++rep) {
        const int kj = tid + rep * 256;
        kpre[rep] = *(const bf16x8*)(kB + (size_t)(mbeg + (kj >> 4)) * C + (kj & 15) * 8);
        const int vj = tid + rep * 256;
        vpre[rep] = *(const bf16x8*)(vB + (size_t)(vj >> 3) * N + mbeg + (vj & 7) * 8);
    }

    for (int it = 0; it < ITERS; ++it) {
        __syncthreads();
        #pragma unroll
        for (int rep = 0; rep < 4; ++rep) {
            const int kj = tid + rep * 256;
            *(bf16x8*)(&k_s[kj >> 4][(kj & 15) * 8]) = kpre[rep];
            const int vj = tid + rep * 256;
            *(bf16x8*)(&v_s[vj >> 3][(vj & 7) * 8]) = vpre[rep];
        }
        __syncthreads();

        if (it + 1 < ITERS) {
            const int m1 = mbeg + (it + 1) * 64;
            #pragma unroll
            for (int rep = 0; rep < 4; ++rep) {
                const int kj = tid + rep * 256;
                kpre[rep] = *(const bf16x8*)(kB + (size_t)(m1 + (kj >> 4)) * C + (kj & 15) * 8);
                const int vj = tid + rep * 256;
                vpre[rep] = *(const bf16x8*)(vB + (size_t)(vj >> 3) * N + m1 + (vj & 7) * 8);
            }
        }

        // S^T = K Q^T for both column sets (shared A fragment)
        floatx4 SA[4], SB[4];
        #pragma unroll
        for (int ct = 0; ct < 4; ++ct) { SA[ct] = fz; SB[ct] = fz; }
        #pragma unroll
        for (int kk = 0; kk < 4; ++kk)
            #pragma unroll
            for (int ct = 0; ct < 4; ++ct) {
                const bf16x8 a = *(bf16x8*)(&k_s[ct * 16 + l15][kk * 32 + quad * 8]);
                SA[ct] = __builtin_amdgcn_mfma_f32_16x16x32_bf16(a, qbA[kk], SA[ct], 0, 0, 0);
                SB[ct] = __builtin_amdgcn_mfma_f32_16x16x32_bf16(a, qbB[kk], SB[ct], 0, 0, 0);
            }

        float rmaxA = -3.0e38f, rmaxB = -3.0e38f;
        #pragma unroll
        for (int ct = 0; ct < 4; ++ct)
            #pragma unroll
            for (int r = 0; r < 4; ++r) {
                const float vA = SA[ct][r] * QSCALE; SA[ct][r] = vA; rmaxA = fmaxf(rmaxA, vA);
                const float vB2 = SB[ct][r] * QSCALE; SB[ct][r] = vB2; rmaxB = fmaxf(rmaxB, vB2);
            }
        rmaxA = fmaxf(rmaxA, __shfl_xor(rmaxA, 16, 64));
        rmaxA = fmaxf(rmaxA, __shfl_xor(rmaxA, 32, 64));
        rmaxB = fmaxf(rmaxB, __shfl_xor(rmaxB, 16, 64));
        rmaxB = fmaxf(rmaxB, __shfl_xor(rmaxB, 32, 64));

        const float mnA = fmaxf(mA, rmaxA);
        const float alphaA = exp2f(mA - mnA);
        mA = mnA;
        const float mnB = fmaxf(mB, rmaxB);
        const float alphaB = exp2f(mB - mnB);
        mB = mnB;

        float rsumA = 0.f, rsumB = 0.f;
        #pragma unroll
        for (int ct = 0; ct < 4; ++ct)
            #pragma unroll
            for (int r = 0; r < 4; ++r) {
                const float pA = exp2f(SA[ct][r] - mA); SA[ct][r] = pA; rsumA += pA;
                const float pB = exp2f(SB[ct][r] - mB); SB[ct][r] = pB; rsumB += pB;
            }
        rsumA += __shfl_xor(rsumA, 16, 64);
        rsumA += __shfl_xor(rsumA, 32, 64);
        rsumB += __shfl_xor(rsumB, 16, 64);
        rsumB += __shfl_xor(rsumB, 32, 64);
        lA = lA * alphaA + rsumA;
        lB = lB * alphaB + rsumB;

        #pragma unroll
        for (int t = 0; t < 8; ++t)
            #pragma unroll
            for (int r = 0; r < 4; ++r) { OA[t][r] *= alphaA; OB[t][r] *= alphaB; }

        #pragma unroll
        for (int ct = 0; ct < 4; ++ct) {
            bf16x4 pkA, pkB;
            #pragma unroll
            for (int r = 0; r < 4; ++r) { pkA[r] = (__bf16)SA[ct][r]; pkB[r] = (__bf16)SB[ct][r]; }
            *(bf16x4*)(&p_s[wv][l15][ct * 16 + quad * 4])      = pkA;
            *(bf16x4*)(&p_s[wv][16 + l15][ct * 16 + quad * 4]) = pkB;
        }

        #pragma unroll
        for (int kk = 0; kk < 2; ++kk) {
            const bf16x8 pbA = *(bf16x8*)(&p_s[wv][l15][kk * 32 + quad * 8]);
            const bf16x8 pbB = *(bf16x8*)(&p_s[wv][16 + l15][kk * 32 + quad * 8]);
            #pragma unroll
            for (int ct = 0; ct < 8; ++ct) {
                const bf16x8 a = *(bf16x8*)(&v_s[ct * 16 + l15][kk * 32 + quad * 8]);
                OA[ct] = __builtin_amdgcn_mfma_f32_16x16x32_bf16(a, pbA, OA[ct], 0, 0, 0);
                OB[ct] = __builtin_amdgcn_mfma_f32_16x16x32_bf16(a, pbB, OB[ct], 0, 0, 0);
            }
        }
    }

    if (PARTIAL) {
        __bf16* OpA = Opart + (((size_t)split * Bn + b) * N + nA) * C;
        __bf16* OpB = OpA + (size_t)16 * C;
        #pragma unroll
        for (int ct = 0; ct < 8; ++ct) {
            bf16x4 oA, oB;
            #pragma unroll
            for (int r = 0; r < 4; ++r) { oA[r] = (__bf16)OA[ct][r]; oB[r] = (__bf16)OB[ct][r]; }
            *(bf16x4*)(OpA + ct * 16 + quad * 4) = oA;
            *(bf16x4*)(OpB + ct * 16 + quad * 4) = oB;
        }
        if (quad == 0) {
            float* mlp = ml + (((size_t)split * Bn + b) * N + nA) * 2;
            mlp[0] = mA; mlp[1] = lA;
            mlp[32] = mB; mlp[33] = lB;            // n+16 -> +32 floats
        }
    } else {
        const float scA = 1.f / lA, scB = 1.f / lB;
        const float gamma = gamma_p[0];
        #pragma unroll
        for (int ct = 0; ct < 8; ++ct)
            #pragma unroll
            for (int r = 0; r < 4; ++r) {
                const int c = ct * 16 + quad * 4 + r;
                const size_t iA = ((size_t)b * C + c) * N + nA;
                out[iA]      = x[iA]      + gamma * OA[ct][r] * scA;
                out[iA + 16] = x[iA + 16] + gamma * OB[ct][r] * scB;
            }
    }
}

// ---------------- combine: merge S splits + epilogue ----------------
// grid (N/32, B), block 256. Base-2 merge.
template <int S>
__global__ __launch_bounds__(256) void combine_kernel(
    const __bf16* __restrict__ Opart, const float* __restrict__ ml,
    const float* __restrict__ x, const float* __restrict__ gamma_p,
    float* __restrict__ out)
{
    constexpr int C = 128, N = 4096, Bn = 2;
    const int b = blockIdx.y, n0 = blockIdx.x * 32;
    const int tid = threadIdx.x;
    __shared__ float cf[S][32];
    __shared__ float ot[32][132];

    if (tid < 32) {
        const int n = n0 + tid;
        float ms[S], ls[S];
        #pragma unroll
        for (int s = 0; s < S; ++s) {
            const float* mlp = ml + (((size_t)s * Bn + b) * N + n) * 2;
            ms[s] = mlp[0]; ls[s] = mlp[1];
        }
        float M = -3.0e38f;
        #pragma unroll
        for (int s = 0; s < S; ++s) M = fmaxf(M, ms[s]);
        float L = 0.f, e[S];
        #pragma unroll
        for (int s = 0; s < S; ++s) { e[s] = exp2f(ms[s] - M); L += e[s] * ls[s]; }
        const float inv = 1.f / L;
        #pragma unroll
        for (int s = 0; s < S; ++s) cf[s][tid] = e[s] * inv;
    }
    __syncthreads();

    #pragma unroll
    for (int rep = 0; rep < 2; ++rep) {
        const int j = tid + rep * 256;
        const int nl = j >> 4, c8 = (j & 15) * 8;
        float acc[8] = {0, 0, 0, 0, 0, 0, 0, 0};
        #pragma unroll
        for (int s = 0; s < S; ++s) {
            const float c0 = cf[s][nl];
            const bf16x8 ov = *(const bf16x8*)(Opart + (((size_t)s * Bn + b) * N + n0 + nl) * C + c8);
            #pragma unroll
            for (int t = 0; t < 8; ++t) acc[t] += c0 * (float)ov[t];
        }
        *(float4*)(&ot[nl][c8])     = *(float4*)(&acc[0]);
        *(float4*)(&ot[nl][c8 + 4]) = *(float4*)(&acc[4]);
    }
    __syncthreads();

    const int nl = tid & 31, cbase = tid >> 5;
    const float gamma = gamma_p[0];
    #pragma unroll
    for (int k = 0; k < 16; ++k) {
        const int c = cbase * 16 + k;
        const size_t idx = ((size_t)b * C + c) * N + n0 + nl;
        out[idx] = x[idx] + gamma * ot[nl][c];
    }
}

extern "C" void kernel_launch(void* const* d_in, const int* in_sizes, int n_in,
                              void* d_out, int out_size, void* d_ws, size_t ws_size,
                              hipStream_t stream) {
    const float* x     = (const float*)d_in[0];
    const float* Wq    = (const float*)d_in[1];
    const float* bq    = (const float*)d_in[2];
    const float* Wk    = (const float*)d_in[3];
    const float* bk    = (const float*)d_in[4];
    const float* Wv    = (const float*)d_in[5];
    const float* bv    = (const float*)d_in[6];
    const float* gamma = (const float*)d_in[7];
    float* out = (float*)d_out;

    constexpr int Bn = 2, C = 128, N = 4096;
    constexpr size_t QKV = (size_t)Bn * N * C;
    __bf16* qT    = (__bf16*)d_ws;
    __bf16* kT    = qT + QKV;
    __bf16* vT2   = kT + QKV;
    __bf16* Opart = vT2 + QKV;
    // sizes for NSPLIT = 8 / 4
    float* ml8 = (float*)(Opart + (size_t)8 * Bn * N * C);
    float* ml4 = (float*)(Opart + (size_t)4 * Bn * N * C);
    const size_t need8 = (char*)(ml8 + (size_t)8 * Bn * N * 2) - (char*)d_ws;
    const size_t need4 = (char*)(ml4 + (size_t)4 * Bn * N * 2) - (char*)d_ws;

    proj_kernel<<<dim3(N / 32, 3, Bn), 128, 0, stream>>>(
        x, Wq, bq, Wk, bk, Wv, bv, qT, kT, vT2);

    if (ws_size >= need8) {
        flash_kernel<8, true><<<32 * 8 * Bn, 256, 0, stream>>>(
            qT, kT, vT2, x, gamma, Opart, ml8, out);
        combine_kernel<8><<<dim3(N / 32, Bn), 256, 0, stream>>>(
            Opart, ml8, x, gamma, out);
    } else if (ws_size >= need4) {
        flash_kernel<4, true><<<32 * 4 * Bn, 256, 0, stream>>>(
            qT, kT, vT2, x, gamma, Opart, ml4, out);
        combine_kernel<4><<<dim3(N / 32, Bn), 256, 0, stream>>>(
            Opart, ml4, x, gamma, out);
    } else {
        flash_kernel<1, false><<<32 * 1 * Bn, 256, 0, stream>>>(
            qT, kT, vT2, x, gamma, nullptr, nullptr, out);
    }
}